// Round 4
// baseline (652.768 us; speedup 1.0000x reference)
//
#include <hip/hip_runtime.h>

#define N0c 1200000
#define N1c 120000
#define N2c 12000
#define E0c 1200000
#define E1c 120000
#define NB0 118   // ceil(N1c/1024)
#define NB1 12    // ceil(N2c/1024)

typedef short short8 __attribute__((ext_vector_type(8)));
typedef float f32x4 __attribute__((ext_vector_type(4)));
typedef unsigned short u16;

__device__ __forceinline__ u16 f2bf(float f) {
    union { float f; unsigned u; } v; v.f = f;
    unsigned r = v.u + 0x7FFFu + ((v.u >> 16) & 1u);
    return (u16)(r >> 16);
}
__device__ __forceinline__ float bf2f(u16 h) {
    union { unsigned u; float f; } v; v.u = ((unsigned)h) << 16;
    return v.f;
}

// ---------------- CSR build, XCD-partitioned (8 private count copies) -------
__global__ void k_hist(const int* __restrict__ dst0, const int* __restrict__ dst1,
                       int* __restrict__ c0, int* __restrict__ c1) {
    int i = blockIdx.x * 256 + threadIdx.x;
    int part = blockIdx.x & 7;
    if (i < E0c) atomicAdd(&c0[part * N1c + dst0[i]], 1);
    else if (i < E0c + E1c) atomicAdd(&c1[part * N2c + dst1[i - E0c]], 1);
}

__global__ void k_scanA(const int* __restrict__ c0, const int* __restrict__ c1,
                        int* __restrict__ partials) {
    __shared__ int sh[256];
    int hop = blockIdx.x >= NB0;
    int blk = hop ? blockIdx.x - NB0 : blockIdx.x;
    const int* c = hop ? c1 : c0;
    int n = hop ? N2c : N1c;
    int d0 = blk * 1024 + threadIdx.x * 4;
    int tsum = 0;
#pragma unroll
    for (int j = 0; j < 4; ++j) {
        int d = d0 + j;
        if (d < n)
#pragma unroll
            for (int k = 0; k < 8; ++k) tsum += c[k * n + d];
    }
    sh[threadIdx.x] = tsum;
    __syncthreads();
    for (int ofs = 128; ofs > 0; ofs >>= 1) {
        if (threadIdx.x < ofs) sh[threadIdx.x] += sh[threadIdx.x + ofs];
        __syncthreads();
    }
    if (threadIdx.x == 0) partials[blockIdx.x] = sh[0];
}

__global__ void k_scanB(int* __restrict__ partials, int* __restrict__ rs0,
                        int* __restrict__ rs1) {
    __shared__ int sh[256];
    int tid = threadIdx.x;
    int v0 = tid < NB0 ? partials[tid] : 0;
    sh[tid] = v0; __syncthreads();
    for (int ofs = 1; ofs < 256; ofs <<= 1) {
        int t = tid >= ofs ? sh[tid - ofs] : 0;
        __syncthreads();
        sh[tid] += t;
        __syncthreads();
    }
    if (tid < NB0) partials[tid] = sh[tid] - v0;
    __syncthreads();
    int v1 = tid < NB1 ? partials[NB0 + tid] : 0;
    sh[tid] = v1; __syncthreads();
    for (int ofs = 1; ofs < 256; ofs <<= 1) {
        int t = tid >= ofs ? sh[tid - ofs] : 0;
        __syncthreads();
        sh[tid] += t;
        __syncthreads();
    }
    if (tid < NB1) partials[NB0 + tid] = sh[tid] - v1;
    if (tid == 0) { rs0[N1c] = E0c; rs1[N2c] = E1c; }
}

__global__ void k_scanC(const int* __restrict__ c0, const int* __restrict__ c1,
                        const int* __restrict__ partials, int* __restrict__ rs0,
                        int* __restrict__ rs1, int* __restrict__ bs0,
                        int* __restrict__ bs1) {
    __shared__ int sh[256];
    int hop = blockIdx.x >= NB0;
    int blk = hop ? blockIdx.x - NB0 : blockIdx.x;
    const int* c = hop ? c1 : c0;
    int* rs = hop ? rs1 : rs0;
    int* bs = hop ? bs1 : bs0;
    int n = hop ? N2c : N1c;
    int tid = threadIdx.x;
    int d0 = blk * 1024 + tid * 4;
    int cv[4][8];
    int tsum = 0;
#pragma unroll
    for (int j = 0; j < 4; ++j)
#pragma unroll
        for (int k = 0; k < 8; ++k) {
            int d = d0 + j;
            int v = (d < n) ? c[k * n + d] : 0;
            cv[j][k] = v; tsum += v;
        }
    sh[tid] = tsum; __syncthreads();
    for (int ofs = 1; ofs < 256; ofs <<= 1) {
        int t = tid >= ofs ? sh[tid - ofs] : 0;
        __syncthreads();
        sh[tid] += t;
        __syncthreads();
    }
    int run = partials[blockIdx.x] + sh[tid] - tsum;
#pragma unroll
    for (int j = 0; j < 4; ++j) {
        int d = d0 + j;
        if (d < n) {
            rs[d] = run;
#pragma unroll
            for (int k = 0; k < 8; ++k) { bs[k * n + d] = run; run += cv[j][k]; }
        }
    }
}

__global__ void k_scat(const int* __restrict__ src0, const int* __restrict__ dst0,
                       const int* __restrict__ src1, const int* __restrict__ dst1,
                       int* __restrict__ c0, int* __restrict__ c1,
                       const int* __restrict__ bs0, const int* __restrict__ bs1,
                       int* __restrict__ eidx0, int* __restrict__ eidx1) {
    int i = blockIdx.x * 256 + threadIdx.x;
    int part = blockIdx.x & 7;
    if (i < E0c) {
        int d = dst0[i];
        int off = atomicSub(&c0[part * N1c + d], 1) - 1;
        eidx0[bs0[part * N1c + d] + off] = src0[i];
    } else if (i < E0c + E1c) {
        int j = i - E0c;
        int d = dst1[j];
        int off = atomicSub(&c1[part * N2c + d], 1) - 1;
        eidx1[bs1[part * N2c + d] + off] = src1[j];
    }
}

// ---------------- weights -> bf16 [Wl | Wr] rows, both layers ----------------
__global__ void k_wcat2(u16* __restrict__ Bt0, const float* __restrict__ Wl0,
                        const float* __restrict__ Wr0, u16* __restrict__ Bt1,
                        const float* __restrict__ Wl1, const float* __restrict__ Wr1) {
    int i = blockIdx.x * blockDim.x + threadIdx.x;
    if (i < 256 * 512) {
        int c = i >> 9, k = i & 511;
        float v = (k < 256) ? Wl0[c * 256 + k] : Wr0[c * 256 + (k - 256)];
        Bt0[i] = f2bf(v);
    } else if (i < 256 * 512 + 64 * 512) {
        int j = i - 256 * 512;
        int c = j >> 9, k = j & 511;
        float v = (k < 256) ? Wl1[c * 256 + k] : Wr1[c * 256 + (k - 256)];
        Bt1[j] = f2bf(v);
    }
}

// swizzled A-LDS byte offset: row stride 1024B; XOR row&7 into 16B-granule bits
// (T2: makes stride-1024 ds_read_b128 column reads ~conflict-free; writes use
// the SAME swizzle so it's bijective per row)
__device__ __forceinline__ int aoff(int row, int byteInRow) {
    return row * 1024 + (byteInRow ^ ((row & 7) << 4));
}

// ---------------- fused layer 0: gather+mean -> LDS A -> MFMA -> relu bf16 ---
// block: 512 thr (8 waves), BM=128 targets, BN=256 (all cols), K=512.
// LDS: A 128KB swizzled + B 20KB (rows padded to 80B).
__global__ __launch_bounds__(512)
void k_fused0(const float* __restrict__ x, const int* __restrict__ eidx,
              const int* __restrict__ rs, const u16* __restrict__ Bt,
              const float* __restrict__ bias, u16* __restrict__ outp) {
    __shared__ u16 Asm[128 * 512];
    __shared__ u16 Bsm[256 * 40];
    const int tid = threadIdx.x;
    const int lane = tid & 63, wid = tid >> 6;
    const long m0 = (long)blockIdx.x * 128;

    // ---- gather phase: wave wid owns local rows wid*16 .. wid*16+15
    for (int t = 0; t < 16; ++t) {
        int wl = wid * 16 + t;
        long w = m0 + wl;
        float a0 = 0.f, a1 = 0.f, a2 = 0.f, a3 = 0.f;
        float s0 = 0.f, s1 = 0.f, s2 = 0.f, s3 = 0.f;
        if (w < N1c) {
            int s = rs[w], e = rs[w + 1];
            int i = s;
            for (; i + 8 <= e; i += 8) {  // 8 independent 1KB row loads in flight
                float4 v[8];
#pragma unroll
                for (int u = 0; u < 8; ++u)
                    v[u] = ((const float4*)(x + (long)eidx[i + u] * 256))[lane];
#pragma unroll
                for (int u = 0; u < 8; ++u) {
                    a0 += v[u].x; a1 += v[u].y; a2 += v[u].z; a3 += v[u].w;
                }
            }
            for (; i + 2 <= e; i += 2) {
                float4 v0 = ((const float4*)(x + (long)eidx[i] * 256))[lane];
                float4 v1 = ((const float4*)(x + (long)eidx[i + 1] * 256))[lane];
                a0 += v0.x + v1.x; a1 += v0.y + v1.y;
                a2 += v0.z + v1.z; a3 += v0.w + v1.w;
            }
            if (i < e) {
                float4 v = ((const float4*)(x + (long)eidx[i] * 256))[lane];
                a0 += v.x; a1 += v.y; a2 += v.z; a3 += v.w;
            }
            int c = e - s; if (c < 1) c = 1;
            float sc = 1.f / (float)c;
            a0 *= sc; a1 *= sc; a2 *= sc; a3 *= sc;
            float4 sv = ((const float4*)(x + w * 256))[lane];
            s0 = sv.x; s1 = sv.y; s2 = sv.z; s3 = sv.w;
        }
        ushort4 oa; oa.x = f2bf(a0); oa.y = f2bf(a1); oa.z = f2bf(a2); oa.w = f2bf(a3);
        *(ushort4*)((char*)Asm + aoff(wl, lane * 8)) = oa;
        ushort4 os; os.x = f2bf(s0); os.y = f2bf(s1); os.z = f2bf(s2); os.w = f2bf(s3);
        *(ushort4*)((char*)Asm + aoff(wl, 512 + lane * 8)) = os;
    }

    // ---- GEMM phase
    const int wm = wid >> 2, wn = wid & 3;
    const int brow = tid >> 1, bcol = (tid & 1) * 16;  // B staging (u16 units)
    f32x4 acc[4][4];
#pragma unroll
    for (int i = 0; i < 4; ++i)
#pragma unroll
        for (int j = 0; j < 4; ++j) acc[i][j] = (f32x4){0.f, 0.f, 0.f, 0.f};
    int4 rb0, rb1;
    {
        const int4* q = (const int4*)(Bt + (long)brow * 512 + bcol);
        rb0 = q[0]; rb1 = q[1];
    }
    __syncthreads();  // Asm visible to all waves
    const int rr = lane & 15, gg = lane >> 4;
    for (int ks = 0; ks < 16; ++ks) {
        {   // write prefetched B tile
            int4* d = (int4*)(Bsm + brow * 40 + bcol);
            d[0] = rb0; d[1] = rb1;
        }
        __syncthreads();
        if (ks < 15) {
            const int4* q = (const int4*)(Bt + (long)brow * 512 + (ks + 1) * 32 + bcol);
            rb0 = q[0]; rb1 = q[1];
        }
        short8 af[4], bv[4];
#pragma unroll
        for (int f = 0; f < 4; ++f) {
            af[f] = *(const short8*)((char*)Asm +
                                     aoff(wm * 64 + f * 16 + rr, ks * 64 + gg * 16));
            bv[f] = *(const short8*)(Bsm + (wn * 64 + f * 16 + rr) * 40 + gg * 8);
        }
#pragma unroll
        for (int i = 0; i < 4; ++i)
#pragma unroll
            for (int j = 0; j < 4; ++j)
                acc[i][j] =
                    __builtin_amdgcn_mfma_f32_16x16x32_bf16(af[i], bv[j], acc[i][j], 0, 0, 0);
        __syncthreads();
    }

    // ---- epilogue: bias + relu + bf16 store
#pragma unroll
    for (int j = 0; j < 4; ++j) {
        int col = wn * 64 + j * 16 + rr;
        float bvl = bias[col];
#pragma unroll
        for (int i = 0; i < 4; ++i) {
            long row = m0 + wm * 64 + i * 16 + gg * 4;
#pragma unroll
            for (int q = 0; q < 4; ++q) {
                long r = row + q;
                if (r < N1c) {
                    float v = acc[i][j][q] + bvl;
                    v = v > 0.f ? v : 0.f;
                    outp[r * 256 + col] = f2bf(v);
                }
            }
        }
    }
}

// ---------------- fused layer 1: gather+mean -> MFMA -> log_softmax -> out ---
// block: 256 thr (4 waves), BM=128 targets, BN=64 cols, K=512.
__global__ __launch_bounds__(256)
void k_fused1(const u16* __restrict__ hsrc, const int* __restrict__ eidx,
              const int* __restrict__ rs, const u16* __restrict__ Bt,
              const float* __restrict__ bias, float* __restrict__ outp) {
    __shared__ u16 Asm[128 * 512];
    __shared__ u16 Bsm[64 * 40];
    const int tid = threadIdx.x;
    const int lane = tid & 63, wid = tid >> 6;
    const long m0 = (long)blockIdx.x * 128;

    // ---- gather phase: wave wid owns local rows wid*32 .. wid*32+31
    for (int t = 0; t < 32; ++t) {
        int wl = wid * 32 + t;
        long w = m0 + wl;
        float a0 = 0.f, a1 = 0.f, a2 = 0.f, a3 = 0.f;
        ushort4 sv; sv.x = 0; sv.y = 0; sv.z = 0; sv.w = 0;
        if (w < N2c) {
            int s = rs[w], e = rs[w + 1];
            int i = s;
            for (; i + 4 <= e; i += 4) {
                ushort4 v0 = ((const ushort4*)(hsrc + (long)eidx[i] * 256))[lane];
                ushort4 v1 = ((const ushort4*)(hsrc + (long)eidx[i + 1] * 256))[lane];
                ushort4 v2 = ((const ushort4*)(hsrc + (long)eidx[i + 2] * 256))[lane];
                ushort4 v3 = ((const ushort4*)(hsrc + (long)eidx[i + 3] * 256))[lane];
                a0 += (bf2f(v0.x) + bf2f(v1.x)) + (bf2f(v2.x) + bf2f(v3.x));
                a1 += (bf2f(v0.y) + bf2f(v1.y)) + (bf2f(v2.y) + bf2f(v3.y));
                a2 += (bf2f(v0.z) + bf2f(v1.z)) + (bf2f(v2.z) + bf2f(v3.z));
                a3 += (bf2f(v0.w) + bf2f(v1.w)) + (bf2f(v2.w) + bf2f(v3.w));
            }
            for (; i < e; ++i) {
                ushort4 v = ((const ushort4*)(hsrc + (long)eidx[i] * 256))[lane];
                a0 += bf2f(v.x); a1 += bf2f(v.y); a2 += bf2f(v.z); a3 += bf2f(v.w);
            }
            int c = e - s; if (c < 1) c = 1;
            float sc = 1.f / (float)c;
            a0 *= sc; a1 *= sc; a2 *= sc; a3 *= sc;
            sv = ((const ushort4*)(hsrc + w * 256))[lane];
        }
        ushort4 oa; oa.x = f2bf(a0); oa.y = f2bf(a1); oa.z = f2bf(a2); oa.w = f2bf(a3);
        *(ushort4*)((char*)Asm + aoff(wl, lane * 8)) = oa;
        *(ushort4*)((char*)Asm + aoff(wl, 512 + lane * 8)) = sv;
    }

    // ---- GEMM phase (4 waves, each 32 rows x 64 cols)
    const int wm = wid;
    const bool bact = tid < 128;
    const int brow = tid >> 1, bcol = (tid & 1) * 16;
    f32x4 acc[2][4];
#pragma unroll
    for (int i = 0; i < 2; ++i)
#pragma unroll
        for (int j = 0; j < 4; ++j) acc[i][j] = (f32x4){0.f, 0.f, 0.f, 0.f};
    int4 rb0, rb1;
    if (bact) {
        const int4* q = (const int4*)(Bt + (long)brow * 512 + bcol);
        rb0 = q[0]; rb1 = q[1];
    }
    __syncthreads();
    const int rr = lane & 15, gg = lane >> 4;
    for (int ks = 0; ks < 16; ++ks) {
        if (bact) {
            int4* d = (int4*)(Bsm + brow * 40 + bcol);
            d[0] = rb0; d[1] = rb1;
        }
        __syncthreads();
        if (bact && ks < 15) {
            const int4* q = (const int4*)(Bt + (long)brow * 512 + (ks + 1) * 32 + bcol);
            rb0 = q[0]; rb1 = q[1];
        }
        short8 af[2], bv[4];
#pragma unroll
        for (int f = 0; f < 2; ++f)
            af[f] = *(const short8*)((char*)Asm +
                                     aoff(wm * 32 + f * 16 + rr, ks * 64 + gg * 16));
#pragma unroll
        for (int j = 0; j < 4; ++j)
            bv[j] = *(const short8*)(Bsm + (j * 16 + rr) * 40 + gg * 8);
#pragma unroll
        for (int i = 0; i < 2; ++i)
#pragma unroll
            for (int j = 0; j < 4; ++j)
                acc[i][j] =
                    __builtin_amdgcn_mfma_f32_16x16x32_bf16(af[i], bv[j], acc[i][j], 0, 0, 0);
        __syncthreads();
    }

    // ---- epilogue: bias + log_softmax (row reduce across 16-lane groups)
#pragma unroll
    for (int i = 0; i < 2; ++i) {
#pragma unroll
        for (int q = 0; q < 4; ++q) {
            long r = m0 + wm * 32 + i * 16 + gg * 4 + q;
            float v[4];
#pragma unroll
            for (int j = 0; j < 4; ++j) v[j] = acc[i][j][q] + bias[j * 16 + rr];
            float mx = fmaxf(fmaxf(v[0], v[1]), fmaxf(v[2], v[3]));
#pragma unroll
            for (int msk = 1; msk < 16; msk <<= 1) mx = fmaxf(mx, __shfl_xor(mx, msk, 16));
            float se = __expf(v[0] - mx) + __expf(v[1] - mx) +
                       __expf(v[2] - mx) + __expf(v[3] - mx);
#pragma unroll
            for (int msk = 1; msk < 16; msk <<= 1) se += __shfl_xor(se, msk, 16);
            float ln = __logf(se);
            if (r < N2c) {
#pragma unroll
                for (int j = 0; j < 4; ++j) outp[r * 64 + j * 16 + rr] = v[j] - mx - ln;
            }
        }
    }
}

extern "C" void kernel_launch(void* const* d_in, const int* in_sizes, int n_in,
                              void* d_out, int out_size, void* d_ws, size_t ws_size,
                              hipStream_t stream) {
    const float* x   = (const float*)d_in[0];
    const int* src0  = (const int*)d_in[1];
    const int* dst0  = (const int*)d_in[2];
    const int* src1  = (const int*)d_in[3];
    const int* dst1  = (const int*)d_in[4];
    const float* Wl0 = (const float*)d_in[5];
    const float* b0  = (const float*)d_in[6];
    const float* Wr0 = (const float*)d_in[7];
    const float* Wl1 = (const float*)d_in[8];
    const float* b1  = (const float*)d_in[9];
    const float* Wr1 = (const float*)d_in[10];

    char* base = (char*)d_ws;
    size_t off = 0;
    auto alloc = [&](size_t bytes) -> void* {
        off = (off + 255) & ~(size_t)255;
        void* p = base + off;
        off += bytes;
        return p;
    };
    int* c0       = (int*)alloc((size_t)8 * N1c * 4);   // 8 XCD-private copies
    int* c1       = (int*)alloc((size_t)8 * N2c * 4);   // (contiguous with c0)
    int* bs0      = (int*)alloc((size_t)8 * N1c * 4);
    int* bs1      = (int*)alloc((size_t)8 * N2c * 4);
    int* rs0      = (int*)alloc((size_t)(N1c + 1) * 4);
    int* rs1      = (int*)alloc((size_t)(N2c + 1) * 4);
    int* partials = (int*)alloc((size_t)(NB0 + NB1) * 4);
    int* eidx0    = (int*)alloc((size_t)E0c * 4);
    int* eidx1    = (int*)alloc((size_t)E1c * 4);
    u16* hbuf     = (u16*)alloc((size_t)N1c * 256 * 2);
    u16* Bt0      = (u16*)alloc((size_t)256 * 512 * 2);
    u16* Bt1      = (u16*)alloc((size_t)64 * 512 * 2);

    // zero both count arrays (contiguous); scat self-restores them to 0
    hipMemsetAsync(c0, 0, (size_t)8 * (N1c + N2c) * 4, stream);

    const int Etot = E0c + E1c;
    k_hist<<<(Etot + 255) / 256, 256, 0, stream>>>(dst0, dst1, c0, c1);
    k_scanA<<<NB0 + NB1, 256, 0, stream>>>(c0, c1, partials);
    k_scanB<<<1, 256, 0, stream>>>(partials, rs0, rs1);
    k_scanC<<<NB0 + NB1, 256, 0, stream>>>(c0, c1, partials, rs0, rs1, bs0, bs1);
    k_scat<<<(Etot + 255) / 256, 256, 0, stream>>>(src0, dst0, src1, dst1,
                                                   c0, c1, bs0, bs1, eidx0, eidx1);

    k_wcat2<<<(256 * 512 + 64 * 512 + 255) / 256, 256, 0, stream>>>(Bt0, Wl0, Wr0,
                                                                    Bt1, Wl1, Wr1);

    // fused layer 0: gather+mean+GEMM+bias+relu -> hbuf (bf16)
    k_fused0<<<(N1c + 127) / 128, 512, 0, stream>>>(x, eidx0, rs0, Bt0, b0, hbuf);

    // fused layer 1: gather+mean+GEMM+bias+log_softmax -> d_out (f32)
    k_fused1<<<(N2c + 127) / 128, 256, 0, stream>>>(hbuf, eidx1, rs1, Bt1, b1,
                                                    (float*)d_out);
}

// Round 5
// 584.697 us; speedup vs baseline: 1.1164x; 1.1164x over previous
//
#include <hip/hip_runtime.h>
#include <stdint.h>

#define N0c 1200000
#define N1c 120000
#define N2c 12000
#define E0c 1200000
#define E1c 120000
#define NB0 118   // ceil(N1c/1024)
#define NB1 12    // ceil(N2c/1024)
#define N1pad 120064
#define N2pad 12032
#define ROWB 80   // bytes per 32-col K-row in tiled layout (64 data + 16 pad)
#define ROWU 40   // u16 per K-row

typedef short short8 __attribute__((ext_vector_type(8)));
typedef float f32x4 __attribute__((ext_vector_type(4)));
typedef unsigned short u16;

__device__ __forceinline__ u16 f2bf(float f) {
    union { float f; unsigned u; } v; v.f = f;
    unsigned r = v.u + 0x7FFFu + ((v.u >> 16) & 1u);
    return (u16)(r >> 16);
}
__device__ __forceinline__ float bf2f(u16 h) {
    union { unsigned u; float f; } v; v.u = ((unsigned)h) << 16;
    return v.f;
}

__device__ __forceinline__ void gload16(const char* g, char* l) {
    __builtin_amdgcn_global_load_lds(
        (const __attribute__((address_space(1))) void*)g,
        (__attribute__((address_space(3))) void*)l, 16, 0, 0);
}

// ---------------- CSR build, XCD-partitioned (8 private count copies) -------
__global__ void k_hist(const int* __restrict__ dst0, const int* __restrict__ dst1,
                       int* __restrict__ c0, int* __restrict__ c1) {
    int i = blockIdx.x * 256 + threadIdx.x;
    int part = blockIdx.x & 7;
    if (i < E0c) atomicAdd(&c0[part * N1c + dst0[i]], 1);
    else if (i < E0c + E1c) atomicAdd(&c1[part * N2c + dst1[i - E0c]], 1);
}

__global__ void k_scanA(const int* __restrict__ c0, const int* __restrict__ c1,
                        int* __restrict__ partials) {
    __shared__ int sh[256];
    int hop = blockIdx.x >= NB0;
    int blk = hop ? blockIdx.x - NB0 : blockIdx.x;
    const int* c = hop ? c1 : c0;
    int n = hop ? N2c : N1c;
    int d0 = blk * 1024 + threadIdx.x * 4;
    int tsum = 0;
#pragma unroll
    for (int j = 0; j < 4; ++j) {
        int d = d0 + j;
        if (d < n)
#pragma unroll
            for (int k = 0; k < 8; ++k) tsum += c[k * n + d];
    }
    sh[threadIdx.x] = tsum;
    __syncthreads();
    for (int ofs = 128; ofs > 0; ofs >>= 1) {
        if (threadIdx.x < ofs) sh[threadIdx.x] += sh[threadIdx.x + ofs];
        __syncthreads();
    }
    if (threadIdx.x == 0) partials[blockIdx.x] = sh[0];
}

__global__ void k_scanB(int* __restrict__ partials, int* __restrict__ rs0,
                        int* __restrict__ rs1) {
    __shared__ int sh[256];
    int tid = threadIdx.x;
    int v0 = tid < NB0 ? partials[tid] : 0;
    sh[tid] = v0; __syncthreads();
    for (int ofs = 1; ofs < 256; ofs <<= 1) {
        int t = tid >= ofs ? sh[tid - ofs] : 0;
        __syncthreads();
        sh[tid] += t;
        __syncthreads();
    }
    if (tid < NB0) partials[tid] = sh[tid] - v0;
    __syncthreads();
    int v1 = tid < NB1 ? partials[NB0 + tid] : 0;
    sh[tid] = v1; __syncthreads();
    for (int ofs = 1; ofs < 256; ofs <<= 1) {
        int t = tid >= ofs ? sh[tid - ofs] : 0;
        __syncthreads();
        sh[tid] += t;
        __syncthreads();
    }
    if (tid < NB1) partials[NB0 + tid] = sh[tid] - v1;
    if (tid == 0) { rs0[N1c] = E0c; rs1[N2c] = E1c; }
}

__global__ void k_scanC(const int* __restrict__ c0, const int* __restrict__ c1,
                        const int* __restrict__ partials, int* __restrict__ rs0,
                        int* __restrict__ rs1, int* __restrict__ bs0,
                        int* __restrict__ bs1) {
    __shared__ int sh[256];
    int hop = blockIdx.x >= NB0;
    int blk = hop ? blockIdx.x - NB0 : blockIdx.x;
    const int* c = hop ? c1 : c0;
    int* rs = hop ? rs1 : rs0;
    int* bs = hop ? bs1 : bs0;
    int n = hop ? N2c : N1c;
    int tid = threadIdx.x;
    int d0 = blk * 1024 + tid * 4;
    int cv[4][8];
    int tsum = 0;
#pragma unroll
    for (int j = 0; j < 4; ++j)
#pragma unroll
        for (int k = 0; k < 8; ++k) {
            int d = d0 + j;
            int v = (d < n) ? c[k * n + d] : 0;
            cv[j][k] = v; tsum += v;
        }
    sh[tid] = tsum; __syncthreads();
    for (int ofs = 1; ofs < 256; ofs <<= 1) {
        int t = tid >= ofs ? sh[tid - ofs] : 0;
        __syncthreads();
        sh[tid] += t;
        __syncthreads();
    }
    int run = partials[blockIdx.x] + sh[tid] - tsum;
#pragma unroll
    for (int j = 0; j < 4; ++j) {
        int d = d0 + j;
        if (d < n) {
            rs[d] = run;
#pragma unroll
            for (int k = 0; k < 8; ++k) { bs[k * n + d] = run; run += cv[j][k]; }
        }
    }
}

__global__ void k_scat(const int* __restrict__ src0, const int* __restrict__ dst0,
                       const int* __restrict__ src1, const int* __restrict__ dst1,
                       int* __restrict__ c0, int* __restrict__ c1,
                       const int* __restrict__ bs0, const int* __restrict__ bs1,
                       int* __restrict__ eidx0, int* __restrict__ eidx1) {
    int i = blockIdx.x * 256 + threadIdx.x;
    int part = blockIdx.x & 7;
    if (i < E0c) {
        int d = dst0[i];
        int off = atomicSub(&c0[part * N1c + d], 1) - 1;
        eidx0[bs0[part * N1c + d] + off] = src0[i];
    } else if (i < E0c + E1c) {
        int j = i - E0c;
        int d = dst1[j];
        int off = atomicSub(&c1[part * N2c + d], 1) - 1;
        eidx1[bs1[part * N2c + d] + off] = src1[j];
    }
}

// ---------------- weights -> bf16 -------------------------------------------
// Bt0: K-tiled [kt=16][256 ch][ROWU] (layer 0, gload_lds GEMM)
// Bt1: row-major [128][512] (layer 1, reg-staged GEMM; rows 64..127 zero)
__global__ void k_wcat2(u16* __restrict__ Bt0, const float* __restrict__ Wl0,
                        const float* __restrict__ Wr0, u16* __restrict__ Bt1,
                        const float* __restrict__ Wl1, const float* __restrict__ Wr1) {
    int i = blockIdx.x * blockDim.x + threadIdx.x;
    if (i < 256 * 512) {
        int c = i >> 9, k = i & 511;
        float v = (k < 256) ? Wl0[c * 256 + k] : Wr0[c * 256 + (k - 256)];
        Bt0[((size_t)(k >> 5) * 256 + c) * ROWU + (k & 31)] = f2bf(v);
    } else if (i < 256 * 512 + 128 * 512) {
        int j = i - 256 * 512;
        int c = j >> 9, k = j & 511;
        float v = 0.f;
        if (c < 64) v = (k < 256) ? Wl1[c * 256 + k] : Wr1[c * 256 + (k - 256)];
        Bt1[j] = f2bf(v);
    }
}

// ---------------- agg layer 0: mean gather -> K-tiled A0 --------------------
// A0[kt][row][ROWU]: kt 0..7 = mean-agg cols, kt 8..15 = self cols.
__global__ void k_agg0(const float* __restrict__ x, const int* __restrict__ eidx,
                       const int* __restrict__ rs, u16* __restrict__ A, int ntgt) {
    int w = (int)((blockIdx.x * blockDim.x + threadIdx.x) >> 6);
    int lane = threadIdx.x & 63;
    if (w >= ntgt) return;
    int s = rs[w], e = rs[w + 1];
    float a0 = 0.f, a1 = 0.f, a2 = 0.f, a3 = 0.f;
    int i = s;
    for (; i + 8 <= e; i += 8) {  // 8 independent 1KB row loads in flight
        float4 v[8];
#pragma unroll
        for (int u = 0; u < 8; ++u)
            v[u] = ((const float4*)(x + (long)eidx[i + u] * 256))[lane];
#pragma unroll
        for (int u = 0; u < 8; ++u) {
            a0 += v[u].x; a1 += v[u].y; a2 += v[u].z; a3 += v[u].w;
        }
    }
    for (; i + 2 <= e; i += 2) {
        float4 v0 = ((const float4*)(x + (long)eidx[i] * 256))[lane];
        float4 v1 = ((const float4*)(x + (long)eidx[i + 1] * 256))[lane];
        a0 += v0.x + v1.x; a1 += v0.y + v1.y; a2 += v0.z + v1.z; a3 += v0.w + v1.w;
    }
    if (i < e) {
        float4 v = ((const float4*)(x + (long)eidx[i] * 256))[lane];
        a0 += v.x; a1 += v.y; a2 += v.z; a3 += v.w;
    }
    int c = e - s; if (c < 1) c = 1;
    float sc = 1.f / (float)c;
    int kt = lane >> 3;
    int cu = (lane & 7) * 4;
    ushort4 oa;
    oa.x = f2bf(a0 * sc); oa.y = f2bf(a1 * sc); oa.z = f2bf(a2 * sc); oa.w = f2bf(a3 * sc);
    *(ushort4*)(A + ((size_t)kt * N1pad + w) * ROWU + cu) = oa;
    float4 sv = ((const float4*)(x + (long)w * 256))[lane];
    ushort4 os;
    os.x = f2bf(sv.x); os.y = f2bf(sv.y); os.z = f2bf(sv.z); os.w = f2bf(sv.w);
    *(ushort4*)(A + ((size_t)(kt + 8) * N1pad + w) * ROWU + cu) = os;
}

// ---------------- agg layer 1: mean gather -> row-major A1 [w][512] ---------
__global__ void k_agg1(const u16* __restrict__ hsrc, const int* __restrict__ eidx,
                       const int* __restrict__ rs, u16* __restrict__ A, int ntgt) {
    int w = (int)((blockIdx.x * blockDim.x + threadIdx.x) >> 6);
    int lane = threadIdx.x & 63;
    if (w >= ntgt) return;
    int s = rs[w], e = rs[w + 1];
    float a0 = 0.f, a1 = 0.f, a2 = 0.f, a3 = 0.f;
    int i = s;
    for (; i + 4 <= e; i += 4) {
        ushort4 v0 = ((const ushort4*)(hsrc + (long)eidx[i] * 256))[lane];
        ushort4 v1 = ((const ushort4*)(hsrc + (long)eidx[i + 1] * 256))[lane];
        ushort4 v2 = ((const ushort4*)(hsrc + (long)eidx[i + 2] * 256))[lane];
        ushort4 v3 = ((const ushort4*)(hsrc + (long)eidx[i + 3] * 256))[lane];
        a0 += (bf2f(v0.x) + bf2f(v1.x)) + (bf2f(v2.x) + bf2f(v3.x));
        a1 += (bf2f(v0.y) + bf2f(v1.y)) + (bf2f(v2.y) + bf2f(v3.y));
        a2 += (bf2f(v0.z) + bf2f(v1.z)) + (bf2f(v2.z) + bf2f(v3.z));
        a3 += (bf2f(v0.w) + bf2f(v1.w)) + (bf2f(v2.w) + bf2f(v3.w));
    }
    for (; i < e; ++i) {
        ushort4 v = ((const ushort4*)(hsrc + (long)eidx[i] * 256))[lane];
        a0 += bf2f(v.x); a1 += bf2f(v.y); a2 += bf2f(v.z); a3 += bf2f(v.w);
    }
    int c = e - s; if (c < 1) c = 1;
    float sc = 1.f / (float)c;
    ushort4 o;
    o.x = f2bf(a0 * sc); o.y = f2bf(a1 * sc); o.z = f2bf(a2 * sc); o.w = f2bf(a3 * sc);
    *(ushort4*)(A + (long)w * 512 + lane * 4) = o;
    ushort4 sv = ((const ushort4*)(hsrc + (long)w * 256))[lane];
    *(ushort4*)(A + (long)w * 512 + 256 + lane * 4) = sv;
}

// ---------------- GEMM0: gload_lds double-buffered, K-tiled operands --------
// 512 thr (8 waves, 2x4), tile 128x256, K=512 in 16 steps of 32.
// LDS/buf: As 128x80B (10 chunks) + Bs 256x80B (20 chunks) = 30720B; dbuf.
__global__ __launch_bounds__(512)
void k_gemm0(const u16* __restrict__ A0, const u16* __restrict__ Bt,
             const float* __restrict__ bias, u16* __restrict__ outp) {
    __shared__ int4 Lbuf[2 * 30720 / 16];
    char* L = (char*)Lbuf;
    const int tid = threadIdx.x;
    const int lane = tid & 63, wid = tid >> 6;
    const int wm = wid >> 2, wn = wid & 3;
    const long m0 = (long)blockIdx.x * 128;

    f32x4 acc[4][4];
#pragma unroll
    for (int i = 0; i < 4; ++i)
#pragma unroll
        for (int j = 0; j < 4; ++j) acc[i][j] = (f32x4){0.f, 0.f, 0.f, 0.f};

    const char* Abase = (const char*)A0 + m0 * ROWB;
    const char* Bbase = (const char*)Bt;

    auto stage = [&](int buf, int kt) {
        char* lb = L + buf * 30720;
        const char* ga = Abase + (size_t)kt * ((size_t)N1pad * ROWB);
        const char* gb = Bbase + (size_t)kt * (256 * ROWB);
#pragma unroll
        for (int c0 = 0; c0 < 4; ++c0) {
            int c = wid + c0 * 8;
            if (c < 30) {
                const char* g = (c < 10) ? (ga + c * 1024) : (gb + (c - 10) * 1024);
                gload16(g + lane * 16, lb + c * 1024);
            }
        }
    };

    stage(0, 0);
    const int rr = lane & 15, gg = lane >> 4;
    for (int ks = 0; ks < 16; ++ks) {
        int cur = ks & 1;
        __syncthreads();  // drains vmcnt(0): buf[cur] staged; readers of buf[cur^1] done
        if (ks + 1 < 16) stage(cur ^ 1, ks + 1);  // overlaps MFMA below
        const char* lb = L + cur * 30720;
        short8 af[4], bv[4];
#pragma unroll
        for (int f = 0; f < 4; ++f) {
            af[f] = *(const short8*)(lb + (wm * 64 + f * 16 + rr) * ROWB + gg * 16);
            bv[f] = *(const short8*)(lb + 10240 + (wn * 64 + f * 16 + rr) * ROWB + gg * 16);
        }
#pragma unroll
        for (int i = 0; i < 4; ++i)
#pragma unroll
            for (int j = 0; j < 4; ++j)
                acc[i][j] =
                    __builtin_amdgcn_mfma_f32_16x16x32_bf16(af[i], bv[j], acc[i][j], 0, 0, 0);
    }

    // epilogue: bias + relu + bf16 store (D row=(lane>>4)*4+q, col=lane&15)
#pragma unroll
    for (int j = 0; j < 4; ++j) {
        int col = wn * 64 + j * 16 + rr;
        float bvl = bias[col];
#pragma unroll
        for (int i = 0; i < 4; ++i) {
            long row = m0 + wm * 64 + i * 16 + gg * 4;
#pragma unroll
            for (int q = 0; q < 4; ++q) {
                long r = row + q;
                if (r < N1c) {
                    float v = acc[i][j][q] + bvl;
                    v = v > 0.f ? v : 0.f;
                    outp[r * 256 + col] = f2bf(v);
                }
            }
        }
    }
}

// ---------------- GEMM1 (layer 1): reg-staged, row-major operands -----------
#define BM 128
#define BK 32
#define LDK 40

template <int WN, bool RELU_BF16>
__global__ __launch_bounds__(128 * WN)
void k_gemm(const u16* __restrict__ A, const u16* __restrict__ Bt,
            const float* __restrict__ bias, void* __restrict__ outp,
            int M, int Ncols, int ldo) {
    constexpr int BN_ = WN * 64;
    constexpr int APT = 4 / WN;
    constexpr int WSH = (WN == 4) ? 2 : 1;
    __shared__ u16 As[BM * LDK];
    __shared__ u16 Bs[BN_ * LDK];
    const int tid = threadIdx.x;
    const int lane = tid & 63, wid = tid >> 6;
    const int wm = wid >> WSH, wn = wid & (WN - 1);
    const long m0 = (long)blockIdx.x * BM;
    const int n0 = blockIdx.y * BN_;
    const int sar = tid / WN, sac = (tid % WN) * (APT * 8);
    const int sbr = tid >> 1, sbc = (tid & 1) * 16;

    f32x4 acc[4][4];
#pragma unroll
    for (int i = 0; i < 4; ++i)
#pragma unroll
        for (int j = 0; j < 4; ++j) acc[i][j] = (f32x4){0.f, 0.f, 0.f, 0.f};

    int4 ra[APT]; int4 rb[2];

    auto load_tile = [&](int ks) {
        int k0 = ks * BK;
        const int4* p = (const int4*)(A + (m0 + sar) * 512 + k0 + sac);
#pragma unroll
        for (int t = 0; t < APT; ++t) ra[t] = p[t];
        const int4* q = (const int4*)(Bt + (long)(n0 + sbr) * 512 + k0 + sbc);
        rb[0] = q[0]; rb[1] = q[1];
    };

    auto write_tile = [&]() {
        int4* da = (int4*)(As + sar * LDK + sac);
#pragma unroll
        for (int t = 0; t < APT; ++t) da[t] = ra[t];
        int4* db = (int4*)(Bs + sbr * LDK + sbc);
        db[0] = rb[0]; db[1] = rb[1];
    };

    load_tile(0);
    const int NK = 512 / BK;
    for (int ks = 0; ks < NK; ++ks) {
        __syncthreads();
        write_tile();
        __syncthreads();
        if (ks + 1 < NK) load_tile(ks + 1);
        short8 af[4], bv[4];
        const int rr = lane & 15, gg = lane >> 4;
#pragma unroll
        for (int f = 0; f < 4; ++f) {
            af[f] = *(const short8*)(As + (wm * 64 + f * 16 + rr) * LDK + gg * 8);
            bv[f] = *(const short8*)(Bs + (wn * 64 + f * 16 + rr) * LDK + gg * 8);
        }
#pragma unroll
        for (int i = 0; i < 4; ++i)
#pragma unroll
            for (int j = 0; j < 4; ++j)
                acc[i][j] =
                    __builtin_amdgcn_mfma_f32_16x16x32_bf16(af[i], bv[j], acc[i][j], 0, 0, 0);
    }

#pragma unroll
    for (int j = 0; j < 4; ++j) {
        int col = n0 + wn * 64 + j * 16 + (lane & 15);
        if (col >= Ncols) continue;
        float bvl = bias[col];
#pragma unroll
        for (int i = 0; i < 4; ++i) {
            long row = m0 + wm * 64 + i * 16 + (lane >> 4) * 4;
#pragma unroll
            for (int q = 0; q < 4; ++q) {
                long r = row + q;
                if (r < M) {
                    float v = acc[i][j][q] + bvl;
                    if (RELU_BF16) {
                        v = v > 0.f ? v : 0.f;
                        ((u16*)outp)[r * (long)ldo + col] = f2bf(v);
                    } else {
                        ((float*)outp)[r * (long)ldo + col] = v;
                    }
                }
            }
        }
    }
}

// ---------------- log_softmax: one wave per row of 64 ----------------
__global__ void k_lsm(const float* __restrict__ lg, float* __restrict__ out, int nrows) {
    int w = (int)((blockIdx.x * blockDim.x + threadIdx.x) >> 6);
    int lane = threadIdx.x & 63;
    if (w >= nrows) return;
    float v = lg[(long)w * 64 + lane];
    float m = v;
    for (int d = 32; d > 0; d >>= 1) m = fmaxf(m, __shfl_xor(m, d, 64));
    float ex = __expf(v - m);
    float s = ex;
    for (int d = 32; d > 0; d >>= 1) s += __shfl_xor(s, d, 64);
    out[(long)w * 64 + lane] = v - m - __logf(s);
}

extern "C" void kernel_launch(void* const* d_in, const int* in_sizes, int n_in,
                              void* d_out, int out_size, void* d_ws, size_t ws_size,
                              hipStream_t stream) {
    const float* x   = (const float*)d_in[0];
    const int* src0  = (const int*)d_in[1];
    const int* dst0  = (const int*)d_in[2];
    const int* src1  = (const int*)d_in[3];
    const int* dst1  = (const int*)d_in[4];
    const float* Wl0 = (const float*)d_in[5];
    const float* b0  = (const float*)d_in[6];
    const float* Wr0 = (const float*)d_in[7];
    const float* Wl1 = (const float*)d_in[8];
    const float* b1  = (const float*)d_in[9];
    const float* Wr1 = (const float*)d_in[10];

    char* base = (char*)d_ws;
    size_t off = 0;
    auto alloc = [&](size_t bytes) -> void* {
        off = (off + 255) & ~(size_t)255;
        void* p = base + off;
        off += bytes;
        return p;
    };
    int* c0       = (int*)alloc((size_t)8 * N1c * 4);
    int* c1       = (int*)alloc((size_t)8 * N2c * 4);
    int* bs0      = (int*)alloc((size_t)8 * N1c * 4);
    int* bs1      = (int*)alloc((size_t)8 * N2c * 4);
    int* rs0      = (int*)alloc((size_t)(N1c + 1) * 4);
    int* rs1      = (int*)alloc((size_t)(N2c + 1) * 4);
    int* partials = (int*)alloc((size_t)(NB0 + NB1) * 4);
    int* eidx0    = (int*)alloc((size_t)E0c * 4);
    int* eidx1    = (int*)alloc((size_t)E1c * 4);
    u16* A0       = (u16*)alloc((size_t)16 * N1pad * ROWU * 2);  // K-tiled
    u16* hbuf     = (u16*)alloc((size_t)N1pad * 256 * 2);
    u16* A1       = (u16*)alloc((size_t)N2pad * 512 * 2);
    u16* Bt0      = (u16*)alloc((size_t)16 * 256 * ROWU * 2);    // K-tiled
    u16* Bt1      = (u16*)alloc((size_t)128 * 512 * 2);
    float* logits = (float*)alloc((size_t)N2pad * 64 * 4);

    hipMemsetAsync(c0, 0, (size_t)8 * (N1c + N2c) * 4, stream);

    const int Etot = E0c + E1c;
    k_hist<<<(Etot + 255) / 256, 256, 0, stream>>>(dst0, dst1, c0, c1);
    k_scanA<<<NB0 + NB1, 256, 0, stream>>>(c0, c1, partials);
    k_scanB<<<1, 256, 0, stream>>>(partials, rs0, rs1);
    k_scanC<<<NB0 + NB1, 256, 0, stream>>>(c0, c1, partials, rs0, rs1, bs0, bs1);
    k_scat<<<(Etot + 255) / 256, 256, 0, stream>>>(src0, dst0, src1, dst1,
                                                   c0, c1, bs0, bs1, eidx0, eidx1);

    k_wcat2<<<(256 * 512 + 128 * 512 + 255) / 256, 256, 0, stream>>>(Bt0, Wl0, Wr0,
                                                                     Bt1, Wl1, Wr1);

    // layer 0
    k_agg0<<<(N1c + 3) / 4, 256, 0, stream>>>(x, eidx0, rs0, A0, N1c);
    k_gemm0<<<N1pad / 128, 512, 0, stream>>>(A0, Bt0, b0, hbuf);

    // layer 1
    k_agg1<<<(N2c + 3) / 4, 256, 0, stream>>>(hbuf, eidx1, rs1, A1, N2c);
    dim3 g1(N2pad / BM, 1);
    k_gemm<2, false><<<g1, 256, 0, stream>>>(A1, Bt1, b1, logits, N2c, 64, 64);

    k_lsm<<<(N2c + 3) / 4, 256, 0, stream>>>(logits, (float*)d_out, N2c);
}

// Round 7
// 532.998 us; speedup vs baseline: 1.2247x; 1.0970x over previous
//
#include <hip/hip_runtime.h>
#include <stdint.h>

#define N0c 1200000
#define N1c 120000
#define N2c 12000
#define E0c 1200000
#define E1c 120000
#define NB0 118   // ceil(N1c/1024)
#define NB1 12    // ceil(N2c/1024)
#define N1pad 120064
#define N2pad 12032
#define ROWB 80   // bytes per 32-col K-row in tiled layout (64 data + 16 pad)
#define ROWU 40   // u16 per K-row
#define HB 5157   // hist blocks = ceil((E0c+E1c)/256)
#define WCB 768   // wcat blocks = (256*512 + 128*512)/256

typedef short short8 __attribute__((ext_vector_type(8)));
typedef float f32x4 __attribute__((ext_vector_type(4)));
typedef unsigned short u16;

__device__ __forceinline__ u16 f2bf(float f) {
    union { float f; unsigned u; } v; v.f = f;
    unsigned r = v.u + 0x7FFFu + ((v.u >> 16) & 1u);
    return (u16)(r >> 16);
}

__device__ __forceinline__ void gload16(const char* g, char* l) {
    __builtin_amdgcn_global_load_lds(
        (const __attribute__((address_space(1))) void*)g,
        (__attribute__((address_space(3))) void*)l, 16, 0, 0);
}

// ---------------- CSR hist + weight convert (independent work, one kernel) --
// Bt0: K-tiled [kt=16][256 ch][ROWU]; Bt1: row-major [128][512], rows>=64 zero
__global__ void k_hist(const int* __restrict__ dst0, const int* __restrict__ dst1,
                       int* __restrict__ c0, int* __restrict__ c1,
                       u16* __restrict__ Bt0, const float* __restrict__ Wl0,
                       const float* __restrict__ Wr0, u16* __restrict__ Bt1,
                       const float* __restrict__ Wl1, const float* __restrict__ Wr1) {
    if (blockIdx.x < HB) {
        int i = blockIdx.x * 256 + threadIdx.x;
        int part = blockIdx.x & 7;
        if (i < E0c) atomicAdd(&c0[part * N1c + dst0[i]], 1);
        else if (i < E0c + E1c) atomicAdd(&c1[part * N2c + dst1[i - E0c]], 1);
    } else {
        int i = (blockIdx.x - HB) * 256 + threadIdx.x;
        if (i < 256 * 512) {
            int c = i >> 9, k = i & 511;
            float v = (k < 256) ? Wl0[c * 256 + k] : Wr0[c * 256 + (k - 256)];
            Bt0[((size_t)(k >> 5) * 256 + c) * ROWU + (k & 31)] = f2bf(v);
        } else {
            int j = i - 256 * 512;
            int c = j >> 9, k = j & 511;
            float v = 0.f;
            if (c < 64) v = (k < 256) ? Wl1[c * 256 + k] : Wr1[c * 256 + (k - 256)];
            Bt1[j] = f2bf(v);
        }
    }
}

__global__ void k_scanA(const int* __restrict__ c0, const int* __restrict__ c1,
                        int* __restrict__ partials) {
    __shared__ int sh[256];
    int hop = blockIdx.x >= NB0;
    int blk = hop ? blockIdx.x - NB0 : blockIdx.x;
    const int* c = hop ? c1 : c0;
    int n = hop ? N2c : N1c;
    int d0 = blk * 1024 + threadIdx.x * 4;
    int tsum = 0;
#pragma unroll
    for (int j = 0; j < 4; ++j) {
        int d = d0 + j;
        if (d < n)
#pragma unroll
            for (int k = 0; k < 8; ++k) tsum += c[k * n + d];
    }
    sh[threadIdx.x] = tsum;
    __syncthreads();
    for (int ofs = 128; ofs > 0; ofs >>= 1) {
        if (threadIdx.x < ofs) sh[threadIdx.x] += sh[threadIdx.x + ofs];
        __syncthreads();
    }
    if (threadIdx.x == 0) partials[blockIdx.x] = sh[0];
}

__global__ void k_scanB(int* __restrict__ partials, int* __restrict__ rs0,
                        int* __restrict__ rs1) {
    __shared__ int sh[256];
    int tid = threadIdx.x;
    int v0 = tid < NB0 ? partials[tid] : 0;
    sh[tid] = v0; __syncthreads();
    for (int ofs = 1; ofs < 256; ofs <<= 1) {
        int t = tid >= ofs ? sh[tid - ofs] : 0;
        __syncthreads();
        sh[tid] += t;
        __syncthreads();
    }
    if (tid < NB0) partials[tid] = sh[tid] - v0;
    __syncthreads();
    int v1 = tid < NB1 ? partials[NB0 + tid] : 0;
    sh[tid] = v1; __syncthreads();
    for (int ofs = 1; ofs < 256; ofs <<= 1) {
        int t = tid >= ofs ? sh[tid - ofs] : 0;
        __syncthreads();
        sh[tid] += t;
        __syncthreads();
    }
    if (tid < NB1) partials[NB0 + tid] = sh[tid] - v1;
    if (tid == 0) { rs0[N1c] = E0c; rs1[N2c] = E1c; }
}

__global__ void k_scanC(const int* __restrict__ c0, const int* __restrict__ c1,
                        const int* __restrict__ partials, int* __restrict__ rs0,
                        int* __restrict__ rs1, int* __restrict__ bs0,
                        int* __restrict__ bs1) {
    __shared__ int sh[256];
    int hop = blockIdx.x >= NB0;
    int blk = hop ? blockIdx.x - NB0 : blockIdx.x;
    const int* c = hop ? c1 : c0;
    int* rs = hop ? rs1 : rs0;
    int* bs = hop ? bs1 : bs0;
    int n = hop ? N2c : N1c;
    int tid = threadIdx.x;
    int d0 = blk * 1024 + tid * 4;
    int cv[4][8];
    int tsum = 0;
#pragma unroll
    for (int j = 0; j < 4; ++j)
#pragma unroll
        for (int k = 0; k < 8; ++k) {
            int d = d0 + j;
            int v = (d < n) ? c[k * n + d] : 0;
            cv[j][k] = v; tsum += v;
        }
    sh[tid] = tsum; __syncthreads();
    for (int ofs = 1; ofs < 256; ofs <<= 1) {
        int t = tid >= ofs ? sh[tid - ofs] : 0;
        __syncthreads();
        sh[tid] += t;
        __syncthreads();
    }
    int run = partials[blockIdx.x] + sh[tid] - tsum;
#pragma unroll
    for (int j = 0; j < 4; ++j) {
        int d = d0 + j;
        if (d < n) {
            rs[d] = run;
#pragma unroll
            for (int k = 0; k < 8; ++k) { bs[k * n + d] = run; run += cv[j][k]; }
        }
    }
}

__global__ void k_scat(const int* __restrict__ src0, const int* __restrict__ dst0,
                       const int* __restrict__ src1, const int* __restrict__ dst1,
                       int* __restrict__ c0, int* __restrict__ c1,
                       const int* __restrict__ bs0, const int* __restrict__ bs1,
                       int* __restrict__ eidx0, int* __restrict__ eidx1) {
    int i = blockIdx.x * 256 + threadIdx.x;
    int part = blockIdx.x & 7;
    if (i < E0c) {
        int d = dst0[i];
        int off = atomicSub(&c0[part * N1c + d], 1) - 1;
        eidx0[bs0[part * N1c + d] + off] = src0[i];
    } else if (i < E0c + E1c) {
        int j = i - E0c;
        int d = dst1[j];
        int off = atomicSub(&c1[part * N2c + d], 1) - 1;
        eidx1[bs1[part * N2c + d] + off] = src1[j];
    }
}

// ---------------- agg layer 0: mean gather only -> K-tiled A0 [kt=8] --------
__global__ void k_agg0(const float* __restrict__ x, const int* __restrict__ eidx,
                       const int* __restrict__ rs, u16* __restrict__ A, int ntgt) {
    int w = (int)((blockIdx.x * blockDim.x + threadIdx.x) >> 6);
    int lane = threadIdx.x & 63;
    if (w >= ntgt) return;
    int s = rs[w], e = rs[w + 1];
    float a0 = 0.f, a1 = 0.f, a2 = 0.f, a3 = 0.f;
    int i = s;
    for (; i + 8 <= e; i += 8) {  // 8 independent 1KB row loads in flight
        f32x4 v[8];
#pragma unroll
        for (int u = 0; u < 8; ++u)
            v[u] = __builtin_nontemporal_load(
                ((const f32x4*)(x + (long)eidx[i + u] * 256)) + lane);
#pragma unroll
        for (int u = 0; u < 8; ++u) {
            a0 += v[u][0]; a1 += v[u][1]; a2 += v[u][2]; a3 += v[u][3];
        }
    }
    for (; i + 2 <= e; i += 2) {
        f32x4 v0 = __builtin_nontemporal_load(
            ((const f32x4*)(x + (long)eidx[i] * 256)) + lane);
        f32x4 v1 = __builtin_nontemporal_load(
            ((const f32x4*)(x + (long)eidx[i + 1] * 256)) + lane);
        a0 += v0[0] + v1[0]; a1 += v0[1] + v1[1];
        a2 += v0[2] + v1[2]; a3 += v0[3] + v1[3];
    }
    if (i < e) {
        f32x4 v = __builtin_nontemporal_load(
            ((const f32x4*)(x + (long)eidx[i] * 256)) + lane);
        a0 += v[0]; a1 += v[1]; a2 += v[2]; a3 += v[3];
    }
    int c = e - s; if (c < 1) c = 1;
    float sc = 1.f / (float)c;
    int kt = lane >> 3;
    int cu = (lane & 7) * 4;
    ushort4 oa;
    oa.x = f2bf(a0 * sc); oa.y = f2bf(a1 * sc); oa.z = f2bf(a2 * sc); oa.w = f2bf(a3 * sc);
    *(ushort4*)(A + ((size_t)kt * N1pad + w) * ROWU + cu) = oa;
}

// ---------------- agg layer 1: mean gather -> row-major A1 [w][512] ---------
__global__ void k_agg1(const u16* __restrict__ hsrc, const int* __restrict__ eidx,
                       const int* __restrict__ rs, u16* __restrict__ A, int ntgt) {
    int w = (int)((blockIdx.x * blockDim.x + threadIdx.x) >> 6);
    int lane = threadIdx.x & 63;
    if (w >= ntgt) return;
    int s = rs[w], e = rs[w + 1];
    float a0 = 0.f, a1 = 0.f, a2 = 0.f, a3 = 0.f;
    auto acc4 = [&](ushort4 v) {
        union { unsigned u; float f; } c0, c1, c2, c3;
        c0.u = (unsigned)v.x << 16; c1.u = (unsigned)v.y << 16;
        c2.u = (unsigned)v.z << 16; c3.u = (unsigned)v.w << 16;
        a0 += c0.f; a1 += c1.f; a2 += c2.f; a3 += c3.f;
    };
    int i = s;
    for (; i + 4 <= e; i += 4) {
        ushort4 v0 = ((const ushort4*)(hsrc + (long)eidx[i] * 256))[lane];
        ushort4 v1 = ((const ushort4*)(hsrc + (long)eidx[i + 1] * 256))[lane];
        ushort4 v2 = ((const ushort4*)(hsrc + (long)eidx[i + 2] * 256))[lane];
        ushort4 v3 = ((const ushort4*)(hsrc + (long)eidx[i + 3] * 256))[lane];
        acc4(v0); acc4(v1); acc4(v2); acc4(v3);
    }
    for (; i < e; ++i) {
        ushort4 v = ((const ushort4*)(hsrc + (long)eidx[i] * 256))[lane];
        acc4(v);
    }
    int c = e - s; if (c < 1) c = 1;
    float sc = 1.f / (float)c;
    ushort4 o;
    o.x = f2bf(a0 * sc); o.y = f2bf(a1 * sc); o.z = f2bf(a2 * sc); o.w = f2bf(a3 * sc);
    *(ushort4*)(A + (long)w * 512 + lane * 4) = o;
    ushort4 sv = ((const ushort4*)(hsrc + (long)w * 256))[lane];
    *(ushort4*)(A + (long)w * 512 + 256 + lane * 4) = sv;
}

// ---------------- GEMM0: agg half via gload_lds, self half direct from x ----
// 512 thr (8 waves, 2x4), tile 128x256, K=512 in 16 steps of 32.
// kt 0..7: A from A0 (K-tiled bf16, gload); kt 8..15: A from x (f32, reg-stage
// + convert). B always gload from K-tiled Bt0. LDS 2x30720B double-buffered.
__global__ __launch_bounds__(512)
void k_gemm0(const u16* __restrict__ A0, const float* __restrict__ x,
             const u16* __restrict__ Bt, const float* __restrict__ bias,
             u16* __restrict__ outp) {
    __shared__ int4 Lbuf[2 * 30720 / 16];
    char* L = (char*)Lbuf;
    const int tid = threadIdx.x;
    const int lane = tid & 63, wid = tid >> 6;
    const int wm = wid >> 2, wn = wid & 3;
    const long m0 = (long)blockIdx.x * 128;

    f32x4 acc[4][4];
#pragma unroll
    for (int i = 0; i < 4; ++i)
#pragma unroll
        for (int j = 0; j < 4; ++j) acc[i][j] = (f32x4){0.f, 0.f, 0.f, 0.f};

    const char* Abase = (const char*)A0 + m0 * ROWB;
    const char* Bbase = (const char*)Bt;
    const int srow = tid >> 2, scq = tid & 3;  // reg-stage mapping (phase B)

    auto stage = [&](int buf, int kt) {
        char* lb = L + buf * 30720;
        const char* gb = Bbase + (size_t)kt * (256 * ROWB);
        if (kt < 8) {
            const char* ga = Abase + (size_t)kt * ((size_t)N1pad * ROWB);
#pragma unroll
            for (int c0 = 0; c0 < 4; ++c0) {
                int c = wid + c0 * 8;
                if (c < 30) {
                    const char* g = (c < 10) ? (ga + c * 1024) : (gb + (c - 10) * 1024);
                    gload16(g + lane * 16, lb + c * 1024);
                }
            }
        } else {
#pragma unroll
            for (int c0 = 0; c0 < 3; ++c0) {
                int c = wid + c0 * 8;
                if (c < 20) gload16(gb + c * 1024 + lane * 16, lb + 10240 + c * 1024);
            }
            // self half: 128 rows x 32 f32 from x, convert to bf16, ds_write
            const f32x4* p =
                (const f32x4*)(x + (m0 + srow) * 256 + (kt - 8) * 32 + scq * 8);
            f32x4 v0 = p[0], v1 = p[1];
            ushort4 h0, h1;
            h0.x = f2bf(v0[0]); h0.y = f2bf(v0[1]); h0.z = f2bf(v0[2]); h0.w = f2bf(v0[3]);
            h1.x = f2bf(v1[0]); h1.y = f2bf(v1[1]); h1.z = f2bf(v1[2]); h1.w = f2bf(v1[3]);
            ushort4* d = (ushort4*)(lb + srow * ROWB + scq * 16);
            d[0] = h0; d[1] = h1;
        }
    };

    stage(0, 0);
    const int rr = lane & 15, gg = lane >> 4;
    for (int ks = 0; ks < 16; ++ks) {
        int cur = ks & 1;
        __syncthreads();  // buf[cur] staged (vmcnt+lgkm drained); buf[cur^1] free
        if (ks + 1 < 16) stage(cur ^ 1, ks + 1);  // overlaps MFMA below
        const char* lb = L + cur * 30720;
        short8 af[4], bv[4];
#pragma unroll
        for (int f = 0; f < 4; ++f) {
            af[f] = *(const short8*)(lb + (wm * 64 + f * 16 + rr) * ROWB + gg * 16);
            bv[f] = *(const short8*)(lb + 10240 + (wn * 64 + f * 16 + rr) * ROWB + gg * 16);
        }
#pragma unroll
        for (int i = 0; i < 4; ++i)
#pragma unroll
            for (int j = 0; j < 4; ++j)
                acc[i][j] =
                    __builtin_amdgcn_mfma_f32_16x16x32_bf16(af[i], bv[j], acc[i][j], 0, 0, 0);
    }

    // epilogue: bias + relu + bf16 store (D row=(lane>>4)*4+q, col=lane&15)
#pragma unroll
    for (int j = 0; j < 4; ++j) {
        int col = wn * 64 + j * 16 + rr;
        float bvl = bias[col];
#pragma unroll
        for (int i = 0; i < 4; ++i) {
            long row = m0 + wm * 64 + i * 16 + gg * 4;
#pragma unroll
            for (int q = 0; q < 4; ++q) {
                long r = row + q;
                if (r < N1c) {
                    float v = acc[i][j][q] + bvl;
                    v = v > 0.f ? v : 0.f;
                    outp[r * 256 + col] = f2bf(v);
                }
            }
        }
    }
}

// ---------------- GEMM1 + fused log_softmax -> d_out ------------------------
// 256 thr (4 waves 2x2), tile 128x128 (cols 64..127 are zero pad), K=512.
__global__ __launch_bounds__(256)
void k_gemm1(const u16* __restrict__ A, const u16* __restrict__ Bt,
             const float* __restrict__ bias, float* __restrict__ outp) {
    __shared__ u16 As[128 * 40];
    __shared__ u16 Bs[128 * 40];
    const int tid = threadIdx.x;
    const int lane = tid & 63, wid = tid >> 6;
    const int wm = wid >> 1, wn = wid & 1;
    const long m0 = (long)blockIdx.x * 128;
    const int sar = tid >> 1, sac = (tid & 1) * 16;

    f32x4 acc[4][4];
#pragma unroll
    for (int i = 0; i < 4; ++i)
#pragma unroll
        for (int j = 0; j < 4; ++j) acc[i][j] = (f32x4){0.f, 0.f, 0.f, 0.f};

    int4 ra[2]; int4 rb[2];
    auto load_tile = [&](int ks) {
        int k0 = ks * 32;
        const int4* p = (const int4*)(A + (m0 + sar) * 512 + k0 + sac);
        ra[0] = p[0]; ra[1] = p[1];
        const int4* q = (const int4*)(Bt + (long)sar * 512 + k0 + sac);
        rb[0] = q[0]; rb[1] = q[1];
    };
    auto write_tile = [&]() {
        int4* da = (int4*)(As + sar * 40 + sac);
        da[0] = ra[0]; da[1] = ra[1];
        int4* db = (int4*)(Bs + sar * 40 + sac);
        db[0] = rb[0]; db[1] = rb[1];
    };

    load_tile(0);
    for (int ks = 0; ks < 16; ++ks) {
        __syncthreads();
        write_tile();
        __syncthreads();
        if (ks + 1 < 16) load_tile(ks + 1);
        short8 af[4], bv[4];
        const int rr = lane & 15, gg = lane >> 4;
#pragma unroll
        for (int f = 0; f < 4; ++f) {
            af[f] = *(const short8*)(As + (wm * 64 + f * 16 + rr) * 40 + gg * 8);
            bv[f] = *(const short8*)(Bs + (wn * 64 + f * 16 + rr) * 40 + gg * 8);
        }
#pragma unroll
        for (int i = 0; i < 4; ++i)
#pragma unroll
            for (int j = 0; j < 4; ++j)
                acc[i][j] =
                    __builtin_amdgcn_mfma_f32_16x16x32_bf16(af[i], bv[j], acc[i][j], 0, 0, 0);
    }

    // epilogue: only wn==0 waves hold real cols (0..63); bias + log_softmax
    const int rr = lane & 15, gg = lane >> 4;
    if (wn == 0) {
#pragma unroll
        for (int i = 0; i < 4; ++i) {
#pragma unroll
            for (int q = 0; q < 4; ++q) {
                long r = m0 + wm * 64 + i * 16 + gg * 4 + q;
                float v[4];
#pragma unroll
                for (int j = 0; j < 4; ++j) v[j] = acc[i][j][q] + bias[j * 16 + rr];
                float mx = fmaxf(fmaxf(v[0], v[1]), fmaxf(v[2], v[3]));
#pragma unroll
                for (int m = 1; m < 16; m <<= 1) mx = fmaxf(mx, __shfl_xor(mx, m, 16));
                float se = __expf(v[0] - mx) + __expf(v[1] - mx) +
                           __expf(v[2] - mx) + __expf(v[3] - mx);
#pragma unroll
                for (int m = 1; m < 16; m <<= 1) se += __shfl_xor(se, m, 16);
                float ln = __logf(se);
                if (r < N2c) {
#pragma unroll
                    for (int j = 0; j < 4; ++j)
                        outp[r * 64 + j * 16 + rr] = v[j] - mx - ln;
                }
            }
        }
    }
}

extern "C" void kernel_launch(void* const* d_in, const int* in_sizes, int n_in,
                              void* d_out, int out_size, void* d_ws, size_t ws_size,
                              hipStream_t stream) {
    const float* x   = (const float*)d_in[0];
    const int* src0  = (const int*)d_in[1];
    const int* dst0  = (const int*)d_in[2];
    const int* src1  = (const int*)d_in[3];
    const int* dst1  = (const int*)d_in[4];
    const float* Wl0 = (const float*)d_in[5];
    const float* b0  = (const float*)d_in[6];
    const float* Wr0 = (const float*)d_in[7];
    const float* Wl1 = (const float*)d_in[8];
    const float* b1  = (const float*)d_in[9];
    const float* Wr1 = (const float*)d_in[10];

    char* base = (char*)d_ws;
    size_t off = 0;
    auto alloc = [&](size_t bytes) -> void* {
        off = (off + 255) & ~(size_t)255;
        void* p = base + off;
        off += bytes;
        return p;
    };
    int* c0       = (int*)alloc((size_t)8 * N1c * 4);
    int* c1       = (int*)alloc((size_t)8 * N2c * 4);
    int* bs0      = (int*)alloc((size_t)8 * N1c * 4);
    int* bs1      = (int*)alloc((size_t)8 * N2c * 4);
    int* rs0      = (int*)alloc((size_t)(N1c + 1) * 4);
    int* rs1      = (int*)alloc((size_t)(N2c + 1) * 4);
    int* partials = (int*)alloc((size_t)(NB0 + NB1) * 4);
    int* eidx0    = (int*)alloc((size_t)E0c * 4);
    int* eidx1    = (int*)alloc((size_t)E1c * 4);
    u16* A0       = (u16*)alloc((size_t)8 * N1pad * ROWU * 2);   // agg half only
    u16* hbuf     = (u16*)alloc((size_t)N1pad * 256 * 2);
    u16* A1       = (u16*)alloc((size_t)N2pad * 512 * 2);
    u16* Bt0      = (u16*)alloc((size_t)16 * 256 * ROWU * 2);    // K-tiled
    u16* Bt1      = (u16*)alloc((size_t)128 * 512 * 2);

    (void)hipMemsetAsync(c0, 0, (size_t)8 * (N1c + N2c) * 4, stream);

    k_hist<<<HB + WCB, 256, 0, stream>>>(dst0, dst1, c0, c1,
                                         Bt0, Wl0, Wr0, Bt1, Wl1, Wr1);
    k_scanA<<<NB0 + NB1, 256, 0, stream>>>(c0, c1, partials);
    k_scanB<<<1, 256, 0, stream>>>(partials, rs0, rs1);
    k_scanC<<<NB0 + NB1, 256, 0, stream>>>(c0, c1, partials, rs0, rs1, bs0, bs1);
    k_scat<<<HB, 256, 0, stream>>>(src0, dst0, src1, dst1,
                                   c0, c1, bs0, bs1, eidx0, eidx1);

    // layer 0: gather (agg half) then GEMM (self read direct from x)
    k_agg0<<<(N1c + 3) / 4, 256, 0, stream>>>(x, eidx0, rs0, A0, N1c);
    k_gemm0<<<N1pad / 128, 512, 0, stream>>>(A0, x, Bt0, b0, hbuf);

    // layer 1: gather then GEMM + fused log_softmax
    k_agg1<<<(N2c + 3) / 4, 256, 0, stream>>>(hbuf, eidx1, rs1, A1, N2c);
    k_gemm1<<<N2pad / 128, 256, 0, stream>>>(A1, Bt1, b1, (float*)d_out);
}